// Round 8
// baseline (111.934 us; speedup 1.0000x reference)
//
#include <hip/hip_runtime.h>

#define BB 32
#define LL 4096
#define DD 1024
#define G1 2048    // k1 grid: 8 blocks/CU, 32 waves/CU (full wave occupancy)
#define K2_TILE 32
#define K3_TILE 16

static __device__ __forceinline__ int imax(int a, int b) { return a > b ? a : b; }
static __device__ __forceinline__ int imin(int a, int b) { return a < b ? a : b; }

// K0: zero sums (24576 f4) + hmid (8192 f4) + out (8192 f4) = 40960 float4.
__global__ __launch_bounds__(256) void k0_zero(float* __restrict__ sums_hmid,
                                               float* __restrict__ out) {
    const int i = blockIdx.x * 256 + threadIdx.x;
    const float4 z = make_float4(0.f, 0.f, 0.f, 0.f);
    if (i < 32768) ((float4*)sums_hmid)[i] = z;
    else ((float4*)out)[i - 32768] = z;
}

// Add rows [beg,end) into acc: 8-deep then 4-deep then scalar tail.
static __device__ __forceinline__ void accum_rows_add(const float* __restrict__ hb,
                                                      int beg, int end, float4& acc) {
    float4 a0 = make_float4(0.f, 0.f, 0.f, 0.f);
    float4 a1 = a0, a2 = a0, a3 = a0, a4 = a0, a5 = a0, a6 = a0, a7 = a0;
    int l = beg;
    for (; l + 8 <= end; l += 8) {
        float4 v0 = *(const float4*)(hb + (size_t)(l + 0) * DD);
        float4 v1 = *(const float4*)(hb + (size_t)(l + 1) * DD);
        float4 v2 = *(const float4*)(hb + (size_t)(l + 2) * DD);
        float4 v3 = *(const float4*)(hb + (size_t)(l + 3) * DD);
        float4 v4 = *(const float4*)(hb + (size_t)(l + 4) * DD);
        float4 v5 = *(const float4*)(hb + (size_t)(l + 5) * DD);
        float4 v6 = *(const float4*)(hb + (size_t)(l + 6) * DD);
        float4 v7 = *(const float4*)(hb + (size_t)(l + 7) * DD);
        a0.x += v0.x; a0.y += v0.y; a0.z += v0.z; a0.w += v0.w;
        a1.x += v1.x; a1.y += v1.y; a1.z += v1.z; a1.w += v1.w;
        a2.x += v2.x; a2.y += v2.y; a2.z += v2.z; a2.w += v2.w;
        a3.x += v3.x; a3.y += v3.y; a3.z += v3.z; a3.w += v3.w;
        a4.x += v4.x; a4.y += v4.y; a4.z += v4.z; a4.w += v4.w;
        a5.x += v5.x; a5.y += v5.y; a5.z += v5.z; a5.w += v5.w;
        a6.x += v6.x; a6.y += v6.y; a6.z += v6.z; a6.w += v6.w;
        a7.x += v7.x; a7.y += v7.y; a7.z += v7.z; a7.w += v7.w;
    }
    for (; l + 4 <= end; l += 4) {
        float4 v0 = *(const float4*)(hb + (size_t)(l + 0) * DD);
        float4 v1 = *(const float4*)(hb + (size_t)(l + 1) * DD);
        float4 v2 = *(const float4*)(hb + (size_t)(l + 2) * DD);
        float4 v3 = *(const float4*)(hb + (size_t)(l + 3) * DD);
        a0.x += v0.x; a0.y += v0.y; a0.z += v0.z; a0.w += v0.w;
        a1.x += v1.x; a1.y += v1.y; a1.z += v1.z; a1.w += v1.w;
        a2.x += v2.x; a2.y += v2.y; a2.z += v2.z; a2.w += v2.w;
        a3.x += v3.x; a3.y += v3.y; a3.z += v3.z; a3.w += v3.w;
    }
    for (; l < end; ++l) {
        float4 v = *(const float4*)(hb + (size_t)l * DD);
        a0.x += v.x; a0.y += v.y; a0.z += v.z; a0.w += v.w;
    }
    acc.x += ((a0.x + a1.x) + (a2.x + a3.x)) + ((a4.x + a5.x) + (a6.x + a7.x));
    acc.y += ((a0.y + a1.y) + (a2.y + a3.y)) + ((a4.y + a5.y) + (a6.y + a7.y));
    acc.z += ((a0.z + a1.z) + (a2.z + a3.z)) + ((a4.z + a5.z) + (a6.z + a7.z));
    acc.w += ((a0.w + a1.w) + (a2.w + a3.w)) + ((a4.w + a5.w) + (a6.w + a7.w));
}

// K1: row-granular balanced decomposition (spread <=1 row). Per (batch,seg)
// piece: one merged accum + one 4-atomic flush into sums[B][3][D].
__global__ __launch_bounds__(256) void k1_sums(const float* __restrict__ h,
                                               const int* __restrict__ sp1,
                                               const int* __restrict__ sp2,
                                               float* __restrict__ sums) {
    const int tid = threadIdx.x;

    int NC = 0;
#pragma unroll
    for (int b = 0; b < BB; ++b)
        NC += sp2[2 * b + 1] - sp1[2 * b] + 1;

    const int q = NC / G1, r = NC % G1;
    const int bk = blockIdx.x;
    int c0 = bk * q + imin(bk, r);
    const int c1 = c0 + q + (bk < r ? 1 : 0);
    if (c0 >= c1) return;

    int b = 0, base = 0, s1, e1, s2, e2, len;
    for (;; ++b) {
        s1 = sp1[2 * b]; e1 = sp1[2 * b + 1];
        s2 = sp2[2 * b]; e2 = sp2[2 * b + 1];
        len = e2 - s1 + 1;
        if (c0 < base + len) break;
        base += len;
    }

    for (;;) {
        const int cend = imin(c1, base + len);
        const int rb = s1 + (c0 - base);
        const int re = s1 + (cend - base);
        const float* hb = h + (size_t)b * LL * DD + (size_t)tid * 4;
        float* dstb = sums + (size_t)b * 3 * DD + (size_t)tid * 4;
        const int lo[3] = {rb, imax(rb, e1 + 1), imax(rb, s2)};
        const int hi[3] = {imin(re, e1 + 1), imin(re, s2), re};
#pragma unroll
        for (int s = 0; s < 3; ++s) {
            if (lo[s] < hi[s]) {
                float4 acc = make_float4(0.f, 0.f, 0.f, 0.f);
                accum_rows_add(hb, lo[s], hi[s], acc);
                float* d = dstb + s * DD;
                atomicAdd(d + 0, acc.x); atomicAdd(d + 1, acc.y);
                atomicAdd(d + 2, acc.z); atomicAdd(d + 3, acc.w);
            }
        }
        c0 = cend;
        if (c0 >= c1) break;
        base += len; ++b;
        s1 = sp1[2 * b]; e1 = sp1[2 * b + 1];
        s2 = sp2[2 * b]; e2 = sp2[2 * b + 1];
        len = e2 - s1 + 1;
    }
}

// K2 (k1b folded): hmid[b][j] += sum_{k in tile} (sums[b][k]*ic) * W1[k][j]
// K2_TILE=32 divides 1024 -> tile never straddles a segment boundary.
__global__ __launch_bounds__(256) void k2_gemm1(const float* __restrict__ sums,
                                                const int* __restrict__ sp1,
                                                const int* __restrict__ sp2,
                                                const float* __restrict__ W1,
                                                float* __restrict__ hmid) {
    __shared__ float cl[K2_TILE * BB];  // [kk][b]
    __shared__ float icl[BB];
    const int tid = threadIdx.x;
    const int j = blockIdx.x * 256 + tid;
    const int k0 = blockIdx.y * K2_TILE;
    const int seg = k0 / DD;

    if (tid < BB) {
        const int b = tid;
        const int s1 = sp1[2 * b], e1 = sp1[2 * b + 1];
        const int s2 = sp2[2 * b], e2 = sp2[2 * b + 1];
        const int cnt = (seg == 0) ? (e1 + 1 - s1) : (seg == 1) ? (s2 - e1 - 1) : (e2 + 1 - s2);
        icl[b] = 1.0f / (float)imax(cnt, 1);
    }
    __syncthreads();
    for (int i = tid; i < K2_TILE * BB; i += 256) {
        const int kk = i / BB;
        const int b = i % BB;
        cl[i] = sums[(size_t)b * (3 * DD) + (k0 + kk)] * icl[b];
    }
    __syncthreads();

    float acc[BB];
#pragma unroll
    for (int b = 0; b < BB; ++b) acc[b] = 0.f;

    const float* w = W1 + (size_t)k0 * DD + j;
#pragma unroll 8
    for (int kk = 0; kk < K2_TILE; ++kk) {
        const float wv = w[(size_t)kk * DD];
        const float4* c4 = (const float4*)(cl + kk * BB);
#pragma unroll
        for (int qq = 0; qq < BB / 4; ++qq) {
            float4 c = c4[qq];
            acc[4 * qq + 0] = fmaf(c.x, wv, acc[4 * qq + 0]);
            acc[4 * qq + 1] = fmaf(c.y, wv, acc[4 * qq + 1]);
            acc[4 * qq + 2] = fmaf(c.z, wv, acc[4 * qq + 2]);
            acc[4 * qq + 3] = fmaf(c.w, wv, acc[4 * qq + 3]);
        }
    }
#pragma unroll
    for (int b = 0; b < BB; ++b) atomicAdd(&hmid[(size_t)b * DD + j], acc[b]);
}

// K3: out[b][j] += sum_{k in tile} relu(hmid[b][k]+b1[k]) * W2[k][j]  (+ b2 once)
__global__ __launch_bounds__(256) void k3_gemm2(const float* __restrict__ hmid,
                                                const float* __restrict__ b1,
                                                const float* __restrict__ W2,
                                                const float* __restrict__ b2,
                                                float* __restrict__ out) {
    __shared__ float al[K3_TILE * BB];  // [kk][b]
    const int tid = threadIdx.x;
    const int j = blockIdx.x * 256 + tid;
    const int k0 = blockIdx.y * K3_TILE;

    for (int i = tid; i < K3_TILE * BB; i += 256) {
        const int kk = i / BB;
        const int b = i % BB;
        const float v = hmid[(size_t)b * DD + (k0 + kk)] + b1[k0 + kk];
        al[i] = fmaxf(v, 0.f);
    }
    __syncthreads();

    float acc[BB];
    const float bias = (blockIdx.y == 0) ? b2[j] : 0.f;
#pragma unroll
    for (int b = 0; b < BB; ++b) acc[b] = bias;

    const float* w = W2 + (size_t)k0 * DD + j;
#pragma unroll 8
    for (int kk = 0; kk < K3_TILE; ++kk) {
        const float wv = w[(size_t)kk * DD];
        const float4* c4 = (const float4*)(al + kk * BB);
#pragma unroll
        for (int qq = 0; qq < BB / 4; ++qq) {
            float4 c = c4[qq];
            acc[4 * qq + 0] = fmaf(c.x, wv, acc[4 * qq + 0]);
            acc[4 * qq + 1] = fmaf(c.y, wv, acc[4 * qq + 1]);
            acc[4 * qq + 2] = fmaf(c.z, wv, acc[4 * qq + 2]);
            acc[4 * qq + 3] = fmaf(c.w, wv, acc[4 * qq + 3]);
        }
    }
#pragma unroll
    for (int b = 0; b < BB; ++b) atomicAdd(&out[(size_t)b * DD + j], acc[b]);
}

extern "C" void kernel_launch(void* const* d_in, const int* in_sizes, int n_in,
                              void* d_out, int out_size, void* d_ws, size_t ws_size,
                              hipStream_t stream) {
    const float* h = (const float*)d_in[0];
    const int* sp1 = (const int*)d_in[1];
    const int* sp2 = (const int*)d_in[2];
    const float* W1 = (const float*)d_in[3];
    const float* b1 = (const float*)d_in[4];
    const float* W2 = (const float*)d_in[5];
    const float* b2 = (const float*)d_in[6];
    float* out = (float*)d_out;

    float* sums = (float*)d_ws;            // BB*3*DD floats
    float* hmid = sums + BB * 3 * DD;      // BB*DD floats (contiguous after sums)

    k0_zero<<<160, 256, 0, stream>>>((float*)d_ws, out);
    k1_sums<<<G1, 256, 0, stream>>>(h, sp1, sp2, sums);
    k2_gemm1<<<dim3(DD / 256, 3 * DD / K2_TILE), 256, 0, stream>>>(sums, sp1, sp2, W1, hmid);
    k3_gemm2<<<dim3(DD / 256, DD / K3_TILE), 256, 0, stream>>>(hmid, b1, W2, b2, out);
}